// Round 14
// baseline (278.037 us; speedup 1.0000x reference)
//
#include <hip/hip_runtime.h>

#define B_ 16
#define T_ 128
#define OBS_ 64
#define SLOTS_ 67
#define E_ 32
#define H_ 4
#define HD_ 8
#define FFN_ 64

typedef _Float16 h2 __attribute__((ext_vector_type(2)));
typedef _Float16 h4 __attribute__((ext_vector_type(4)));
typedef _Float16 h8 __attribute__((ext_vector_type(8)));
typedef __fp16 mh4 __attribute__((ext_vector_type(4)));
typedef __fp16 mh8 __attribute__((ext_vector_type(8)));
typedef float fx4 __attribute__((ext_vector_type(4)));
typedef float fx2 __attribute__((ext_vector_type(2)));
union H4u { h4 v; h2 h[2]; };

// fp16 weight block layout (halves): Wq 0 | Wk 1024 | Wv 2048 | Wo 3072 |
// Wg 4096 | Wvl 6144 | Wout 8192  (10240 halves per transformer block)
#define WBLK 10240
#define X16_BYTES (B_ * T_ * SLOTS_ * E_ * 2)  // 8,781,824 (X stored fp16)
#define W16_BYTES (5 * WBLK * 2)
#define ROPE_OFF (X16_BYTES + W16_BYTES)       // float2[T_][4] cos/sin table

// DPP-based group reductions: shfl_xor lowers to ds_swizzle (DS pipe, ~30cy
// latency per step); DPP row ops are plain VALU (~4cy dep). Subgroup
// generated by the XOR set covers the whole group, so the sums match.
template <int CTRL>
__device__ __forceinline__ float dpp_add(float v) {
  int s = __builtin_amdgcn_update_dpp(0, __builtin_bit_cast(int, v), CTRL,
                                      0xF, 0xF, true);
  return v + __builtin_bit_cast(float, s);
}
__device__ __forceinline__ float red8(float v) {   // sum over 8-lane groups
  v = dpp_add<0xB1>(v);    // quad_perm [1,0,3,2] : xor1
  v = dpp_add<0x4E>(v);    // quad_perm [2,3,0,1] : xor2
  v = dpp_add<0x141>(v);   // row_half_mirror     : xor7
  return v;
}
__device__ __forceinline__ float bfly16(float v) { // sum over 16-lane groups
  v = dpp_add<0xB1>(v);    // xor1
  v = dpp_add<0x4E>(v);    // xor2
  v = dpp_add<0x141>(v);   // xor7
  v = dpp_add<0x140>(v);   // row_mirror          : xor15
  return v;
}
__device__ __forceinline__ h2 pkrtz(float x, float y) {
  return __builtin_bit_cast(h2, __builtin_amdgcn_cvt_pkrtz(x, y));
}
__device__ __forceinline__ float rcp_(float x) { return __builtin_amdgcn_rcpf(x); }
__device__ __forceinline__ float rsq_(float x) { return __builtin_amdgcn_rsqf(x); }
__device__ __forceinline__ fx4 mfma16(h8 a, h8 b, fx4 c) {
  return __builtin_amdgcn_mfma_f32_16x16x32_f16(
      __builtin_bit_cast(mh8, a), __builtin_bit_cast(mh8, b), c, 0, 0, 0);
}
__device__ __forceinline__ fx4 mfma16k16(h4 a, h4 b, fx4 c) {
  return __builtin_amdgcn_mfma_f32_16x16x16f16(
      __builtin_bit_cast(mh4, a), __builtin_bit_cast(mh4, b), c, 0, 0, 0);
}

// Inline-asm register pins: the empty asm opaquely consumes/produces the
// value, so the compiler cannot re-sink the feeding ds_read into later
// loops (r13: +4.5 µs total from pinning phase-3 hoists).
__device__ __forceinline__ h8 pin8(h8 v) {
  fx4 t = __builtin_bit_cast(fx4, v);
  asm volatile("" : "+v"(t));
  return __builtin_bit_cast(h8, t);
}
__device__ __forceinline__ h4 pin4(h4 v) {
  fx2 t = __builtin_bit_cast(fx2, v);
  asm volatile("" : "+v"(t));
  return __builtin_bit_cast(h4, t);
}

// LDS bank-conflict swizzles: XOR whole 8-half (16 B) chunks so row-stride
// bank aliasing becomes 2-way (free).
__device__ __forceinline__ int sw32(int row, int col) {  // stride-32 buffers
  return row * 32 + (col ^ (((row >> 1) & 3) << 3));
}
__device__ __forceinline__ int sw64(int row, int col) {  // stride-64 (ffnb)
  return row * 64 + (col ^ ((row & 7) << 3));
}

// ---------------- setup: weight fp16 conversion + rope table ---------------
struct WPtrs {
  const float *sWq, *sWk, *sWv, *sWo, *sWg, *sWvl, *sWout;
  const float *tWq, *tWk, *tWv, *tWo, *tWg, *tWvl, *tWout;
};

#define CVT_BLOCKS 100

__global__ __launch_bounds__(256) void setup_kernel(
    WPtrs p, _Float16* __restrict__ dst, float2* __restrict__ rope) {
  if (blockIdx.x < CVT_BLOCKS) {
    int i = blockIdx.x * 256 + threadIdx.x;  // pair index
    const int total_pairs = 5 * WBLK / 2;    // 25600
    if (i >= total_pairs) return;
    int blk = i / (WBLK / 2);
    int f = (i % (WBLK / 2)) * 2;
    bool sp = blk < 3;
    int bi = sp ? blk : blk - 3;
    const float* src;
    int o;
    if (f < 1024)      { src = (sp ? p.sWq : p.tWq) + bi * 1024;  o = f; }
    else if (f < 2048) { src = (sp ? p.sWk : p.tWk) + bi * 1024;  o = f - 1024; }
    else if (f < 3072) { src = (sp ? p.sWv : p.tWv) + bi * 1024;  o = f - 2048; }
    else if (f < 4096) { src = (sp ? p.sWo : p.tWo) + bi * 1024;  o = f - 3072; }
    else if (f < 6144) { src = (sp ? p.sWg : p.tWg) + bi * 2048;  o = f - 4096; }
    else if (f < 8192) { src = (sp ? p.sWvl : p.tWvl) + bi * 2048; o = f - 6144; }
    else               { src = (sp ? p.sWout : p.tWout) + bi * 2048; o = f - 8192; }
    ((h2*)dst)[i] = pkrtz(src[o], src[o + 1]);
  } else {
    // rope table: rope[pos*4+j] = (cos, sin) of pos * 10000^{-j/4}
    for (int i = threadIdx.x; i < T_ * 4; i += 256) {
      int pos = i >> 2, j = i & 3;
      float th = __builtin_amdgcn_exp2f(-(float)j * 3.3219280948873623f);
      float sv, cv;
      __sincosf((float)pos * th, &sv, &cv);
      rope[i] = make_float2(cv, sv);
    }
  }
}

// embed-source pointers for the EMBED (layer-0 spatial) instantiation
struct EPtrs {
  const float *obs, *Wval, *bval, *innw, *dimemb, *cls;
};

// ================= full attention block, all GEMM-shaped math on MFMA ======
// r13-best structure (272.7 µs): 4 waves, 5 barriers, DPP reductions,
// embed fused into spatial layer 0, PINNED phase-3 hoists. r14 widens the
// TEMPORAL phase-3 interleave from 2 to 4 chains (one kt sweep feeds four
// independent S->exp->PV chains; r3's quad failed only because the unpinned
// hoist at cap 102 spilled — pins + cap 128 make it fit: ~116 VGPR).
// SV = valid rows, SP = padded rows (multiple of 16).
// LDS (halves): [hb SP*32 | qb SP*32 | kb SP*32 | vT].
//   hb: h -> o -> h2 ; ffnb (SV*64) overlays qb+kb.
// sw32/sw64 chunk-XOR swizzles keep b128 LDS reads ~2-way bank-aliased.
// Attention: S^T = K · (Q head-masked)^T (16x16x32); exp'd C-frag of S^T is
// the B-operand of 16x16x16 PV (O^T = vT · P^T). PV A-rows 8..15 carry ONES
// so C rows 8..15 hold the softmax denominator.
// Lessons held: 4-wave blocks (r5/r7 nulls), 5-barrier mapping (r11 -3%),
// budget < 128 VGPR (r3/r5 spills; WRITE_SIZE is the tripwire).
template <int SV, int SP, bool TEMPORAL, bool LAST, bool EMBED>
__device__ __forceinline__ void block_body(
    _Float16* __restrict__ X, const _Float16* __restrict__ W16,
    const float* __restrict__ norm4, const float* __restrict__ qkn,
    const float2* __restrict__ rope, const float* __restrict__ fnw,
    float* __restrict__ out, const EPtrs ep, int bid) {
  constexpr int MT = SP / 16;
  constexpr int MTW = (MT + 3) / 4;  // mt tiles per wave (ceil)
  constexpr int VSTRIDE = TEMPORAL ? 128 : 168;
  constexpr int VROWS = TEMPORAL ? 32 : 33;
  __shared__ __align__(16) _Float16 smem[SP * 96 + VROWS * VSTRIDE];
  _Float16* hb = smem;
  _Float16* qb = smem + SP * 32;
  _Float16* kb = smem + SP * 64;
  _Float16* vT = smem + SP * 96;   // [d][s] transposed V
  _Float16* ffnb = qb;             // ffn overlay (SV*64 over qb+kb)

  const int tid = threadIdx.x;
  const int l = tid & 63, wv = tid >> 6;
  const int lm = l & 15, lq = l >> 4, hd = l & 7;

  auto vt_idx = [](int d, int s) {
    if (TEMPORAL) return d * 128 + (((s & ~15) ^ ((d & 7) << 4)) | (s & 15));
    return d * VSTRIDE + s;
  };

  int base, stride;
  if (TEMPORAL) {
    int b = bid / SLOTS_;
    int slot = bid % SLOTS_;
    base = (b * T_ * SLOTS_ + slot) * E_;
    stride = SLOTS_ * E_;
  } else {
    base = bid * 2 * SLOTS_ * E_;  // contiguous 134-row slab
    stride = E_;
  }

  const float nw0a = norm4[lm],      nw0b = norm4[16 + lm];
  const float nw1a = norm4[32 + lm], nw1b = norm4[48 + lm];
  const float nw2a = norm4[64 + lm], nw2b = norm4[80 + lm];
  const float nw3a = norm4[96 + lm], nw3b = norm4[112 + lm];
  const fx4 fz = {0.f, 0.f, 0.f, 0.f};
  const float qw = qkn[hd], kw = qkn[8 + hd];
  const float qscale = 0.35355339059327373f * 1.4426950408889634f;  // 1/sqrt(8)*log2e

  // ---- phase 1: x -> regs (C-layout); h = rmsnorm(x) -> hb ----
  // EMBED (spatial layer 0): compute token embedding + input rmsnorm here
  // instead of loading X (r12, removes the 17152-block embed pass).
  float xr[MTW][4][2];
  float wva, wvb, bva, bvb, ina, inb;
  if (EMBED) {
    wva = ep.Wval[lm]; wvb = ep.Wval[16 + lm];
    bva = ep.bval[lm]; bvb = ep.bval[16 + lm];
    ina = ep.innw[lm]; inb = ep.innw[16 + lm];
  }
#pragma unroll
  for (int t = 0; t < MTW; t++) {
    int mt = wv + 4 * t;
    if (mt < MT) {
#pragma unroll
      for (int r = 0; r < 4; r++) {
        int s = mt * 16 + lq * 4 + r;
        bool ok = (SV == SP) || (s < SV);
        if (EMBED) {
          float v0 = 0.f, v1 = 0.f;
          if (ok) {
            int frame = (s >= SLOTS_) ? 1 : 0;
            int slot = s - frame * SLOTS_;
            int bt = bid * 2 + frame;
            if (slot < OBS_) {
              float o = ep.obs[bt * OBS_ + slot];
              v0 = o * wva + bva + ep.dimemb[slot * E_ + lm];
              v1 = o * wvb + bvb + ep.dimemb[slot * E_ + 16 + lm];
            } else {
              v0 = ep.cls[(slot - OBS_) * E_ + lm];
              v1 = ep.cls[(slot - OBS_) * E_ + 16 + lm];
            }
            float ss = bfly16(v0 * v0 + v1 * v1);
            float ninv = rsq_(ss * (1.0f / E_) + 1e-6f);
            v0 = v0 * ninv * ina;
            v1 = v1 * ninv * inb;
          }
          xr[t][r][0] = v0;
          xr[t][r][1] = v1;
        } else {
          int off = base + s * stride;
          xr[t][r][0] = ok ? (float)X[off + lm] : 0.f;
          xr[t][r][1] = ok ? (float)X[off + 16 + lm] : 0.f;
        }
      }
    }
  }
#pragma unroll
  for (int t = 0; t < MTW; t++) {
    int mt = wv + 4 * t;
    if (mt < MT) {
#pragma unroll
      for (int r = 0; r < 4; r++) {
        int s = mt * 16 + lq * 4 + r;
        float p = bfly16(xr[t][r][0] * xr[t][r][0] + xr[t][r][1] * xr[t][r][1]);
        float inv = rsq_(p * (1.0f / E_) + 1e-6f);
        if (SV == SP || s < SV) {
          hb[sw32(s, lm)] = (_Float16)(xr[t][r][0] * inv * nw0a);
          hb[sw32(s, 16 + lm)] = (_Float16)(xr[t][r][1] * inv * nw0b);
        }
      }
    }
  }
  __syncthreads();

  // ---- phase 2: q/k/v = MFMA(h, W) + head rmsnorm + RoPE; v -> vT ----
  for (int u = wv; u < MT * 2; u += 4) {
    const int mt = u >> 1, nt = u & 1;
    h8 aH = *(const h8*)(hb + sw32(mt * 16 + lm, lq * 8));
    float rc[4], rs[4];
    if (TEMPORAL) {
#pragma unroll
      for (int r = 0; r < 4; r++) {
        float2 cs = rope[(mt * 16 + lq * 4 + r) * 4 + (hd & 3)];
        rc[r] = cs.x; rs[r] = cs.y;
      }
    }
    const int d = nt * 16 + lm;
    h8 bq = *(const h8*)(W16 + (nt * 16 + lm) * 32 + lq * 8);
    h8 bk = *(const h8*)(W16 + 1024 + (nt * 16 + lm) * 32 + lq * 8);
    h8 bv = *(const h8*)(W16 + 2048 + (nt * 16 + lm) * 32 + lq * 8);
    fx4 aq = mfma16(aH, bq, fz);
    fx4 ak = mfma16(aH, bk, fz);
    fx4 av = mfma16(aH, bv, fz);
#pragma unroll
    for (int r = 0; r < 4; r++) {
      int s = mt * 16 + lq * 4 + r;
      float q1 = aq[r], k1 = ak[r];
      float qv = q1 * rsq_(red8(q1 * q1) * 0.125f + 1e-6f) * qw;
      float kv = k1 * rsq_(red8(k1 * k1) * 0.125f + 1e-6f) * kw;
      if (TEMPORAL) {
        float qp = __shfl_xor(qv, 4);
        float kp = __shfl_xor(kv, 4);
        qv = (hd < 4) ? (qv * rc[r] - qp * rs[r]) : (qv * rc[r] + qp * rs[r]);
        kv = (hd < 4) ? (kv * rc[r] - kp * rs[r]) : (kv * rc[r] + kp * rs[r]);
      }
      if (SV == SP || s < SV) {
        qb[sw32(s, d)] = (_Float16)(qv * qscale);  // exp2-ready
        kb[sw32(s, d)] = (_Float16)kv;
      }
    }
    // v -> vT[d][s], packed pairs (cols s0..s0+3, same 16-block)
    const int s0 = mt * 16 + lq * 4;
    const int va = vt_idx(d, s0);
    if (SV == SP || s0 + 1 < SV) *(h2*)(vT + va) = pkrtz(av[0], av[1]);
    if (SV == SP || s0 + 3 < SV) *(h2*)(vT + va + 2) = pkrtz(av[2], av[3]);
  }
  if (!TEMPORAL) {
    // zero vT cols [134,160) so padded-K PV chunks multiply P*0 (finite)
    for (int idx = tid; idx < 32 * 13; idx += 256) {
      int d = idx / 13, c = 2 * SLOTS_ + 2 * (idx % 13);
      *(h2*)(vT + d * VSTRIDE + c) = pkrtz(0.f, 0.f);
    }
    // ones row 32: PV A-rows 8..15 read it -> C rows 8..15 = softmax denom
    for (int idx = tid; idx < VSTRIDE / 2; idx += 256) {
      *(h2*)(vT + 32 * VSTRIDE + 2 * idx) = pkrtz(1.f, 1.f);
    }
  }
  __syncthreads();

  // ---- phase 3: MFMA attention, PINNED hoist, quad/pair interleaved ----
  {
    const int h = wv;
    const h8 z8 = {};
    const h4 ones4 = {(_Float16)1.f, (_Float16)1.f, (_Float16)1.f, (_Float16)1.f};
    const bool vlane = (lm < 8);
    const int dv = h * 8 + (lm & 7);
    const int vrow = (!TEMPORAL && !vlane) ? 32 : dv;

    auto loadK = [&](int kt) {
      return pin8(*(const h8*)(kb + sw32(kt * 16 + lm, lq * 8)));
    };
    auto loadV = [&](int kt) {
      h4 v = *(const h4*)(vT + vt_idx(vrow, kt * 16 + lq * 4));
      v = pin4(v);
      return (TEMPORAL && !vlane) ? ones4 : v;
    };
    auto loadQ = [&](int mt) {
      h8 b = pin8(*(const h8*)(qb + sw32(mt * 16 + lm, lq * 8)));
      return (lq == h) ? b : z8;  // keep head-h dims only
    };
    auto maskx = [&](float x, int kidx, int mode, int q) {
      // mode 0: none; 1: keep kidx<67; 2: keep kidx>=67; 3: keep kidx<134;
      // 4: keep same-sequence & kidx<134
      if (mode == 1) return (kidx < SLOTS_) ? x : 0.f;
      if (mode == 2) return (kidx >= SLOTS_) ? x : 0.f;
      if (mode == 3) return (kidx < 2 * SLOTS_) ? x : 0.f;
      if (mode == 4) {
        bool ok = (kidx < 2 * SLOTS_) && ((kidx < SLOTS_) == (q < SLOTS_));
        return ok ? x : 0.f;
      }
      return x;
    };
    auto pvstep = [&](const h4& av, int kt, int mode, int q, const fx4& sc,
                      fx4& oacc) {
      float ev[4];
#pragma unroll
      for (int r = 0; r < 4; r++) {
        int kidx = kt * 16 + lq * 4 + r;
        ev[r] = maskx(__builtin_amdgcn_exp2f(sc[r]), kidx, mode, q);
      }
      H4u pT;
      pT.h[0] = pkrtz(ev[0], ev[1]); pT.h[1] = pkrtz(ev[2], ev[3]);
      oacc = mfma16k16(av, pT.v, oacc);
    };
    auto finish = [&](int mt, fx4& oa) {
      int q = mt * 16 + lm;
      // C rows 8..15 (lanes lq>=2) hold lsum; swap over to lanes lq<2
      float lsum = __shfl_xor(oa[0], 32);
      float inv = rcp_(lsum);
      if (lq < 2 && (SV == SP || q < SV)) {
        H4u ov;
        ov.h[0] = pkrtz(oa[0] * inv, oa[1] * inv);
        ov.h[1] = pkrtz(oa[2] * inv, oa[3] * inv);
        *(h4*)(hb + sw32(q, h * 8 + lq * 4)) = ov.v;  // h dead -> o
      }
    };

    if (TEMPORAL) {
      // pinned hoist aK/aV once; QUAD interleave: one kt sweep feeds 4
      // independent chains (mt 0..3, then 4..7). ~116 VGPR peak.
      h8 aK[MT]; h4 aV[MT];
#pragma unroll
      for (int kt = 0; kt < MT; kt++) { aK[kt] = loadK(kt); aV[kt] = loadV(kt); }
#pragma unroll
      for (int half = 0; half < 2; half++) {
        const int m0 = half * 4;
        h8 bQ0 = loadQ(m0 + 0), bQ1 = loadQ(m0 + 1);
        h8 bQ2 = loadQ(m0 + 2), bQ3 = loadQ(m0 + 3);
        fx4 o0 = fz, o1 = fz, o2 = fz, o3 = fz;
#pragma unroll
        for (int kt = 0; kt < MT; kt++) {
          fx4 s0 = mfma16(aK[kt], bQ0, fz);
          fx4 s1 = mfma16(aK[kt], bQ1, fz);
          fx4 s2 = mfma16(aK[kt], bQ2, fz);
          fx4 s3 = mfma16(aK[kt], bQ3, fz);
          pvstep(aV[kt], kt, 0, 0, s0, o0);
          pvstep(aV[kt], kt, 0, 0, s1, o1);
          pvstep(aV[kt], kt, 0, 0, s2, o2);
          pvstep(aV[kt], kt, 0, 0, s3, o3);
        }
        finish(m0 + 0, o0);
        finish(m0 + 1, o1);
        finish(m0 + 2, o2);
        finish(m0 + 3, o3);
      }
    } else {
      // section A: kt window 0..4, pairs (0,1),(2,3) — seq0 queries
      {
        h8 aKw[5]; h4 aVw[5];
#pragma unroll
        for (int kt = 0; kt < 5; kt++) { aKw[kt] = loadK(kt); aVw[kt] = loadV(kt); }
#pragma unroll
        for (int mtp = 0; mtp < 2; mtp++) {
          h8 bQ0 = loadQ(2 * mtp), bQ1 = loadQ(2 * mtp + 1);
          fx4 o0 = fz, o1 = fz;
#pragma unroll
          for (int kt = 0; kt < 5; kt++) {
            int mode = (kt == 4) ? 1 : 0;
            fx4 s0 = mfma16(aKw[kt], bQ0, fz);
            fx4 s1 = mfma16(aKw[kt], bQ1, fz);
            pvstep(aVw[kt], kt, mode, 0, s0, o0);
            pvstep(aVw[kt], kt, mode, 0, s1, o1);
          }
          finish(2 * mtp, o0);
          finish(2 * mtp + 1, o1);
        }
      }
      // section B: boundary tile mt=4, full kt sweep, per-q mask
      {
        h8 aKw[9]; h4 aVw[9];
#pragma unroll
        for (int kt = 0; kt < 9; kt++) { aKw[kt] = loadK(kt); aVw[kt] = loadV(kt); }
        h8 bQ = loadQ(4);
        fx4 oa = fz;
        const int q = 4 * 16 + lm;
#pragma unroll
        for (int kt = 0; kt < 9; kt++) {
          fx4 sc = mfma16(aKw[kt], bQ, fz);
          pvstep(aVw[kt], kt, 4, q, sc, oa);
        }
        finish(4, oa);
      }
      // section C: kt window 4..8, pairs (5,6),(7,8) — seq1 queries
      {
        h8 aKw[5]; h4 aVw[5];
#pragma unroll
        for (int kt = 0; kt < 5; kt++) {
          aKw[kt] = loadK(kt + 4); aVw[kt] = loadV(kt + 4);
        }
#pragma unroll
        for (int mtp = 0; mtp < 2; mtp++) {
          int m0 = 5 + 2 * mtp;
          h8 bQ0 = loadQ(m0), bQ1 = loadQ(m0 + 1);
          fx4 o0 = fz, o1 = fz;
#pragma unroll
          for (int kt = 0; kt < 5; kt++) {
            int mode = (kt == 0) ? 2 : (kt == 4 ? 3 : 0);
            fx4 s0 = mfma16(aKw[kt], bQ0, fz);
            fx4 s1 = mfma16(aKw[kt], bQ1, fz);
            pvstep(aVw[kt], kt + 4, mode, 0, s0, o0);
            pvstep(aVw[kt], kt + 4, mode, 0, s1, o1);
          }
          finish(m0, o0);
          finish(m0 + 1, o1);
        }
      }
    }
  }
  __syncthreads();

  // ---- phase 4 (fused): ao = MFMA(o, Wo); x += rms(ao); h2 = rms(x) -> hb.
#pragma unroll
  for (int t = 0; t < MTW; t++) {
    int mt = wv + 4 * t;
    if (mt < MT) {
      h8 aO = *(const h8*)(hb + sw32(mt * 16 + lm, lq * 8));
      h8 b0 = *(const h8*)(W16 + 3072 + lm * 32 + lq * 8);
      h8 b1 = *(const h8*)(W16 + 3072 + (16 + lm) * 32 + lq * 8);
      fx4 a0 = mfma16(aO, b0, fz);
      fx4 a1 = mfma16(aO, b1, fz);
#pragma unroll
      for (int r = 0; r < 4; r++) {
        int s = mt * 16 + lq * 4 + r;
        float p = bfly16(a0[r] * a0[r] + a1[r] * a1[r]);
        float inv = rsq_(p * (1.0f / E_) + 1e-6f);
        xr[t][r][0] += a0[r] * inv * nw1a;
        xr[t][r][1] += a1[r] * inv * nw1b;
        float q2 = bfly16(xr[t][r][0] * xr[t][r][0] + xr[t][r][1] * xr[t][r][1]);
        float inv2 = rsq_(q2 * (1.0f / E_) + 1e-6f);
        if (SV == SP || s < SV) {
          hb[sw32(s, lm)] = (_Float16)(xr[t][r][0] * inv2 * nw2a);
          hb[sw32(s, 16 + lm)] = (_Float16)(xr[t][r][1] * inv2 * nw2b);
        }
      }
    }
  }
  __syncthreads();

  // ---- phase 5: ffn = silu(MFMA(h2,Wg)) * MFMA(h2,Wvl) -> ffnb ----
  for (int u = wv; u < MT * 4; u += 4) {
    const int mt = u >> 2, nt = u & 3;
    h8 aH2 = *(const h8*)(hb + sw32(mt * 16 + lm, lq * 8));
    h8 bg = *(const h8*)(W16 + 4096 + (nt * 16 + lm) * 32 + lq * 8);
    h8 bl = *(const h8*)(W16 + 6144 + (nt * 16 + lm) * 32 + lq * 8);
    fx4 g = mfma16(aH2, bg, fz);
    fx4 vvv = mfma16(aH2, bl, fz);
#pragma unroll
    for (int r = 0; r < 4; r++) {
      int s = mt * 16 + lq * 4 + r;
      if (SV == SP || s < SV) {
        float gg = g[r];
        float sg = gg * rcp_(1.0f + __builtin_amdgcn_exp2f(gg * -1.4426950408889634f));
        ffnb[sw64(s, nt * 16 + lm)] = (_Float16)(sg * vvv[r]);
      }
    }
  }
  __syncthreads();

  // ---- phase 6 (fused): out = MFMA(ffn, Wout^T); x += rms(out); store X ----
#pragma unroll
  for (int t = 0; t < MTW; t++) {
    int mt = wv + 4 * t;
    if (mt < MT) {
      const int row = mt * 16 + lm;
      h8 a0 = *(const h8*)(ffnb + sw64(row, lq * 8));
      h8 a1 = *(const h8*)(ffnb + sw64(row, 32 + lq * 8));
      h8 b00 = *(const h8*)(W16 + 8192 + lm * 64 + lq * 8);
      h8 b01 = *(const h8*)(W16 + 8192 + lm * 64 + 32 + lq * 8);
      h8 b10 = *(const h8*)(W16 + 8192 + (16 + lm) * 64 + lq * 8);
      h8 b11 = *(const h8*)(W16 + 8192 + (16 + lm) * 64 + 32 + lq * 8);
      fx4 o0 = mfma16(a1, b01, mfma16(a0, b00, fz));
      fx4 o1 = mfma16(a1, b11, mfma16(a0, b10, fz));
#pragma unroll
      for (int r = 0; r < 4; r++) {
        int s = mt * 16 + lq * 4 + r;
        float p = bfly16(o0[r] * o0[r] + o1[r] * o1[r]);
        float inv = rsq_(p * (1.0f / E_) + 1e-6f);
        xr[t][r][0] += o0[r] * inv * nw3a;
        xr[t][r][1] += o1[r] * inv * nw3b;
        if (SV == SP || s < SV) {
          int off = base + s * stride;
          X[off + lm] = (_Float16)xr[t][r][0];
          X[off + 16 + lm] = (_Float16)xr[t][r][1];
        }
      }
      // fold final rmsnorm + output extract into last spatial layer: the 48
      // output tokens are rows 131..133 of blocks with (bid % (T_/2)) == 63
      if (LAST && mt == MT - 1 && (bid & (T_ / 2 - 1)) == (T_ / 2 - 1)) {
        const int b = bid / (T_ / 2);
#pragma unroll
        for (int r = 0; r < 4; r++) {
          int s = mt * 16 + lq * 4 + r;
          int j = s - (SLOTS_ + OBS_);
          float p2 = bfly16(xr[t][r][0] * xr[t][r][0] + xr[t][r][1] * xr[t][r][1]);
          if (j >= 0 && j < 3) {
            float inv2 = rsq_(p2 * (1.0f / E_) + 1e-6f);
            out[j * (B_ * E_) + b * E_ + lm] = xr[t][r][0] * inv2 * fnw[lm];
            out[j * (B_ * E_) + b * E_ + 16 + lm] = xr[t][r][1] * inv2 * fnw[16 + lm];
          }
        }
      }
    }
  }
}

__global__ __launch_bounds__(256, 4) void attn_spatial_embed_kernel(
    _Float16* __restrict__ X, const _Float16* __restrict__ W16,
    const float* __restrict__ norm4, const float* __restrict__ qkn,
    EPtrs ep) {
  block_body<2 * SLOTS_, 144, false, false, true>(
      X, W16, norm4, qkn, nullptr, nullptr, nullptr, ep, blockIdx.x);
}

__global__ __launch_bounds__(256, 4) void attn_spatial_kernel(
    _Float16* __restrict__ X, const _Float16* __restrict__ W16,
    const float* __restrict__ norm4, const float* __restrict__ qkn) {
  EPtrs ep{};
  block_body<2 * SLOTS_, 144, false, false, false>(
      X, W16, norm4, qkn, nullptr, nullptr, nullptr, ep, blockIdx.x);
}

__global__ __launch_bounds__(256, 4) void attn_spatial_last_kernel(
    _Float16* __restrict__ X, const _Float16* __restrict__ W16,
    const float* __restrict__ norm4, const float* __restrict__ qkn,
    const float* __restrict__ fnw, float* __restrict__ out) {
  EPtrs ep{};
  block_body<2 * SLOTS_, 144, false, true, false>(
      X, W16, norm4, qkn, nullptr, fnw, out, ep, blockIdx.x);
}

__global__ __launch_bounds__(256, 4) void attn_temporal_kernel(
    _Float16* __restrict__ X, const _Float16* __restrict__ W16,
    const float* __restrict__ norm4, const float* __restrict__ qkn,
    const float2* __restrict__ rope) {
  EPtrs ep{};
  block_body<T_, 128, true, false, false>(
      X, W16, norm4, qkn, rope, nullptr, nullptr, ep, blockIdx.x);
}

extern "C" void kernel_launch(void* const* d_in, const int* in_sizes, int n_in,
                              void* d_out, int out_size, void* d_ws, size_t ws_size,
                              hipStream_t stream) {
  (void)in_sizes; (void)n_in; (void)out_size; (void)ws_size;
  const float* obs          = (const float*)d_in[0];
  const float* W_val        = (const float*)d_in[1];
  const float* b_val        = (const float*)d_in[2];
  const float* input_norm_w = (const float*)d_in[3];
  const float* dim_embed    = (const float*)d_in[4];
  const float* cls_tokens   = (const float*)d_in[5];
  const float* final_norm_w = (const float*)d_in[6];
  const float* s_n4   = (const float*)d_in[14];
  const float* s_qkn  = (const float*)d_in[15];
  const float* t_n4   = (const float*)d_in[23];
  const float* t_qkn  = (const float*)d_in[24];

  _Float16* X = (_Float16*)d_ws;  // fp16 residual stream, 8.78 MB
  _Float16* W16 = (_Float16*)((char*)d_ws + X16_BYTES);  // 5*10240 halves
  float2* rope = (float2*)((char*)d_ws + ROPE_OFF);      // 4 KB cos/sin
  float* out = (float*)d_out;

  WPtrs wp;
  wp.sWq   = (const float*)d_in[7];
  wp.sWk   = (const float*)d_in[8];
  wp.sWv   = (const float*)d_in[9];
  wp.sWo   = (const float*)d_in[10];
  wp.sWg   = (const float*)d_in[11];
  wp.sWvl  = (const float*)d_in[12];
  wp.sWout = (const float*)d_in[13];
  wp.tWq   = (const float*)d_in[16];
  wp.tWk   = (const float*)d_in[17];
  wp.tWv   = (const float*)d_in[18];
  wp.tWo   = (const float*)d_in[19];
  wp.tWg   = (const float*)d_in[20];
  wp.tWvl  = (const float*)d_in[21];
  wp.tWout = (const float*)d_in[22];

  EPtrs ep;
  ep.obs = obs; ep.Wval = W_val; ep.bval = b_val;
  ep.innw = input_norm_w; ep.dimemb = dim_embed; ep.cls = cls_tokens;

  setup_kernel<<<CVT_BLOCKS + 1, 256, 0, stream>>>(wp, W16, rope);

  const int N4 = 4 * E_;   // 128
  const int QN = 2 * HD_;  // 16

  // layer 0 spatial computes the embed in phase 1 (no separate embed pass)
  attn_spatial_embed_kernel<<<B_ * T_ / 2, 256, 0, stream>>>(
      X, W16, s_n4, s_qkn, ep);
  attn_temporal_kernel<<<B_ * SLOTS_, 256, 0, stream>>>(
      X, W16 + 3 * WBLK, t_n4, t_qkn, rope);
  attn_spatial_kernel<<<B_ * T_ / 2, 256, 0, stream>>>(
      X, W16 + 1 * WBLK, s_n4 + N4, s_qkn + QN);
  attn_temporal_kernel<<<B_ * SLOTS_, 256, 0, stream>>>(
      X, W16 + 4 * WBLK, t_n4 + N4, t_qkn + QN, rope);
  attn_spatial_last_kernel<<<B_ * T_ / 2, 256, 0, stream>>>(
      X, W16 + 2 * WBLK, s_n4 + 2 * N4, s_qkn + 2 * QN, final_norm_w, out);
}

// Round 15
// 268.131 us; speedup vs baseline: 1.0369x; 1.0369x over previous
//
#include <hip/hip_runtime.h>

#define B_ 16
#define T_ 128
#define OBS_ 64
#define SLOTS_ 67
#define E_ 32
#define H_ 4
#define HD_ 8
#define FFN_ 64

typedef _Float16 h2 __attribute__((ext_vector_type(2)));
typedef _Float16 h4 __attribute__((ext_vector_type(4)));
typedef _Float16 h8 __attribute__((ext_vector_type(8)));
typedef __fp16 mh4 __attribute__((ext_vector_type(4)));
typedef __fp16 mh8 __attribute__((ext_vector_type(8)));
typedef float fx4 __attribute__((ext_vector_type(4)));
typedef float fx2 __attribute__((ext_vector_type(2)));
union H4u { h4 v; h2 h[2]; };

// fp16 weight block layout (halves): Wq 0 | Wk 1024 | Wv 2048 | Wo 3072 |
// Wg 4096 | Wvl 6144 | Wout 8192  (10240 halves per transformer block)
#define WBLK 10240
#define X16_BYTES (B_ * T_ * SLOTS_ * E_ * 2)  // 8,781,824 (X stored fp16)
#define W16_BYTES (5 * WBLK * 2)
#define ROPE_OFF (X16_BYTES + W16_BYTES)       // float2[T_][4] cos/sin table

// DPP-based group reductions: shfl_xor lowers to ds_swizzle (DS pipe, ~30cy
// latency per step); DPP row ops are plain VALU (~4cy dep). Subgroup
// generated by the XOR set covers the whole group, so the sums match.
template <int CTRL>
__device__ __forceinline__ float dpp_add(float v) {
  int s = __builtin_amdgcn_update_dpp(0, __builtin_bit_cast(int, v), CTRL,
                                      0xF, 0xF, true);
  return v + __builtin_bit_cast(float, s);
}
__device__ __forceinline__ float red8(float v) {   // sum over 8-lane groups
  v = dpp_add<0xB1>(v);    // quad_perm [1,0,3,2] : xor1
  v = dpp_add<0x4E>(v);    // quad_perm [2,3,0,1] : xor2
  v = dpp_add<0x141>(v);   // row_half_mirror     : xor7
  return v;
}
__device__ __forceinline__ float bfly16(float v) { // sum over 16-lane groups
  v = dpp_add<0xB1>(v);    // xor1
  v = dpp_add<0x4E>(v);    // xor2
  v = dpp_add<0x141>(v);   // xor7
  v = dpp_add<0x140>(v);   // row_mirror          : xor15
  return v;
}
__device__ __forceinline__ h2 pkrtz(float x, float y) {
  return __builtin_bit_cast(h2, __builtin_amdgcn_cvt_pkrtz(x, y));
}
__device__ __forceinline__ float rcp_(float x) { return __builtin_amdgcn_rcpf(x); }
__device__ __forceinline__ float rsq_(float x) { return __builtin_amdgcn_rsqf(x); }
__device__ __forceinline__ fx4 mfma16(h8 a, h8 b, fx4 c) {
  return __builtin_amdgcn_mfma_f32_16x16x32_f16(
      __builtin_bit_cast(mh8, a), __builtin_bit_cast(mh8, b), c, 0, 0, 0);
}
__device__ __forceinline__ fx4 mfma16k16(h4 a, h4 b, fx4 c) {
  return __builtin_amdgcn_mfma_f32_16x16x16f16(
      __builtin_bit_cast(mh4, a), __builtin_bit_cast(mh4, b), c, 0, 0, 0);
}

// Inline-asm register pins: the empty asm opaquely consumes/produces the
// value, so the compiler cannot re-sink the feeding load into later loops
// (r13: +4.5 µs from pinning phase-3 hoists; r14 lesson: pins enable
// hoisting but wider interleave past 2 chains regresses).
__device__ __forceinline__ h8 pin8(h8 v) {
  fx4 t = __builtin_bit_cast(fx4, v);
  asm volatile("" : "+v"(t));
  return __builtin_bit_cast(h8, t);
}
__device__ __forceinline__ h4 pin4(h4 v) {
  fx2 t = __builtin_bit_cast(fx2, v);
  asm volatile("" : "+v"(t));
  return __builtin_bit_cast(h4, t);
}

// LDS bank-conflict swizzles: XOR whole 8-half (16 B) chunks so row-stride
// bank aliasing becomes 2-way (free).
__device__ __forceinline__ int sw32(int row, int col) {  // stride-32 buffers
  return row * 32 + (col ^ (((row >> 1) & 3) << 3));
}
__device__ __forceinline__ int sw64(int row, int col) {  // stride-64 (ffnb)
  return row * 64 + (col ^ ((row & 7) << 3));
}

// ---------------- setup: weight fp16 conversion + rope table ---------------
struct WPtrs {
  const float *sWq, *sWk, *sWv, *sWo, *sWg, *sWvl, *sWout;
  const float *tWq, *tWk, *tWv, *tWo, *tWg, *tWvl, *tWout;
};

#define CVT_BLOCKS 100

__global__ __launch_bounds__(256) void setup_kernel(
    WPtrs p, _Float16* __restrict__ dst, float2* __restrict__ rope) {
  if (blockIdx.x < CVT_BLOCKS) {
    int i = blockIdx.x * 256 + threadIdx.x;  // pair index
    const int total_pairs = 5 * WBLK / 2;    // 25600
    if (i >= total_pairs) return;
    int blk = i / (WBLK / 2);
    int f = (i % (WBLK / 2)) * 2;
    bool sp = blk < 3;
    int bi = sp ? blk : blk - 3;
    const float* src;
    int o;
    if (f < 1024)      { src = (sp ? p.sWq : p.tWq) + bi * 1024;  o = f; }
    else if (f < 2048) { src = (sp ? p.sWk : p.tWk) + bi * 1024;  o = f - 1024; }
    else if (f < 3072) { src = (sp ? p.sWv : p.tWv) + bi * 1024;  o = f - 2048; }
    else if (f < 4096) { src = (sp ? p.sWo : p.tWo) + bi * 1024;  o = f - 3072; }
    else if (f < 6144) { src = (sp ? p.sWg : p.tWg) + bi * 2048;  o = f - 4096; }
    else if (f < 8192) { src = (sp ? p.sWvl : p.tWvl) + bi * 2048; o = f - 6144; }
    else               { src = (sp ? p.sWout : p.tWout) + bi * 2048; o = f - 8192; }
    ((h2*)dst)[i] = pkrtz(src[o], src[o + 1]);
  } else {
    // rope table: rope[pos*4+j] = (cos, sin) of pos * 10000^{-j/4}
    for (int i = threadIdx.x; i < T_ * 4; i += 256) {
      int pos = i >> 2, j = i & 3;
      float th = __builtin_amdgcn_exp2f(-(float)j * 3.3219280948873623f);
      float sv, cv;
      __sincosf((float)pos * th, &sv, &cv);
      rope[i] = make_float2(cv, sv);
    }
  }
}

// embed-source pointers for the EMBED (layer-0 spatial) instantiation
struct EPtrs {
  const float *obs, *Wval, *bval, *innw, *dimemb, *cls;
};

// ================= full attention block, all GEMM-shaped math on MFMA ======
// r13-best structure (272.7 µs): 4 waves, 5 barriers, DPP reductions,
// embed fused into spatial layer 0, PINNED phase-3 hoists with PAIR
// interleave (r14: quad regressed — pairs are optimal). r15 additionally
// hoists + pins the LOOP-INVARIANT weight loads: phase 2's bq/bk/bv
// (nt = u&1 is wave-constant), phase 5's bg/bl (nt = u&3 wave-constant),
// and phases 4/6's mt-invariant B operands — removes ~20 redundant global
// loads + vmcnt waits from each block's serial path.
// SV = valid rows, SP = padded rows (multiple of 16).
// LDS (halves): [hb SP*32 | qb SP*32 | kb SP*32 | vT].
//   hb: h -> o -> h2 ; ffnb (SV*64) overlays qb+kb.
// sw32/sw64 chunk-XOR swizzles keep b128 LDS reads ~2-way bank-aliased.
// Attention: S^T = K · (Q head-masked)^T (16x16x32); exp'd C-frag of S^T is
// the B-operand of 16x16x16 PV (O^T = vT · P^T). PV A-rows 8..15 carry ONES
// so C rows 8..15 hold the softmax denominator.
// Lessons held: 4-wave blocks (r5/r7), 5 barriers (r11), pair interleave
// (r14), budget < 128 VGPR (r3/r5 spills; WRITE_SIZE is the tripwire).
template <int SV, int SP, bool TEMPORAL, bool LAST, bool EMBED>
__device__ __forceinline__ void block_body(
    _Float16* __restrict__ X, const _Float16* __restrict__ W16,
    const float* __restrict__ norm4, const float* __restrict__ qkn,
    const float2* __restrict__ rope, const float* __restrict__ fnw,
    float* __restrict__ out, const EPtrs ep, int bid) {
  constexpr int MT = SP / 16;
  constexpr int MTW = (MT + 3) / 4;  // mt tiles per wave (ceil)
  constexpr int VSTRIDE = TEMPORAL ? 128 : 168;
  constexpr int VROWS = TEMPORAL ? 32 : 33;
  __shared__ __align__(16) _Float16 smem[SP * 96 + VROWS * VSTRIDE];
  _Float16* hb = smem;
  _Float16* qb = smem + SP * 32;
  _Float16* kb = smem + SP * 64;
  _Float16* vT = smem + SP * 96;   // [d][s] transposed V
  _Float16* ffnb = qb;             // ffn overlay (SV*64 over qb+kb)

  const int tid = threadIdx.x;
  const int l = tid & 63, wv = tid >> 6;
  const int lm = l & 15, lq = l >> 4, hd = l & 7;

  auto vt_idx = [](int d, int s) {
    if (TEMPORAL) return d * 128 + (((s & ~15) ^ ((d & 7) << 4)) | (s & 15));
    return d * VSTRIDE + s;
  };

  int base, stride;
  if (TEMPORAL) {
    int b = bid / SLOTS_;
    int slot = bid % SLOTS_;
    base = (b * T_ * SLOTS_ + slot) * E_;
    stride = SLOTS_ * E_;
  } else {
    base = bid * 2 * SLOTS_ * E_;  // contiguous 134-row slab
    stride = E_;
  }

  const float nw0a = norm4[lm],      nw0b = norm4[16 + lm];
  const float nw1a = norm4[32 + lm], nw1b = norm4[48 + lm];
  const float nw2a = norm4[64 + lm], nw2b = norm4[80 + lm];
  const float nw3a = norm4[96 + lm], nw3b = norm4[112 + lm];
  const fx4 fz = {0.f, 0.f, 0.f, 0.f};
  const float qw = qkn[hd], kw = qkn[8 + hd];
  const float qscale = 0.35355339059327373f * 1.4426950408889634f;  // 1/sqrt(8)*log2e

  // ---- phase 1: x -> regs (C-layout); h = rmsnorm(x) -> hb ----
  // EMBED (spatial layer 0): compute token embedding + input rmsnorm here
  // instead of loading X (r12, removes the 17152-block embed pass).
  float xr[MTW][4][2];
  float wva, wvb, bva, bvb, ina, inb;
  if (EMBED) {
    wva = ep.Wval[lm]; wvb = ep.Wval[16 + lm];
    bva = ep.bval[lm]; bvb = ep.bval[16 + lm];
    ina = ep.innw[lm]; inb = ep.innw[16 + lm];
  }
#pragma unroll
  for (int t = 0; t < MTW; t++) {
    int mt = wv + 4 * t;
    if (mt < MT) {
#pragma unroll
      for (int r = 0; r < 4; r++) {
        int s = mt * 16 + lq * 4 + r;
        bool ok = (SV == SP) || (s < SV);
        if (EMBED) {
          float v0 = 0.f, v1 = 0.f;
          if (ok) {
            int frame = (s >= SLOTS_) ? 1 : 0;
            int slot = s - frame * SLOTS_;
            int bt = bid * 2 + frame;
            if (slot < OBS_) {
              float o = ep.obs[bt * OBS_ + slot];
              v0 = o * wva + bva + ep.dimemb[slot * E_ + lm];
              v1 = o * wvb + bvb + ep.dimemb[slot * E_ + 16 + lm];
            } else {
              v0 = ep.cls[(slot - OBS_) * E_ + lm];
              v1 = ep.cls[(slot - OBS_) * E_ + 16 + lm];
            }
            float ss = bfly16(v0 * v0 + v1 * v1);
            float ninv = rsq_(ss * (1.0f / E_) + 1e-6f);
            v0 = v0 * ninv * ina;
            v1 = v1 * ninv * inb;
          }
          xr[t][r][0] = v0;
          xr[t][r][1] = v1;
        } else {
          int off = base + s * stride;
          xr[t][r][0] = ok ? (float)X[off + lm] : 0.f;
          xr[t][r][1] = ok ? (float)X[off + 16 + lm] : 0.f;
        }
      }
    }
  }
#pragma unroll
  for (int t = 0; t < MTW; t++) {
    int mt = wv + 4 * t;
    if (mt < MT) {
#pragma unroll
      for (int r = 0; r < 4; r++) {
        int s = mt * 16 + lq * 4 + r;
        float p = bfly16(xr[t][r][0] * xr[t][r][0] + xr[t][r][1] * xr[t][r][1]);
        float inv = rsq_(p * (1.0f / E_) + 1e-6f);
        if (SV == SP || s < SV) {
          hb[sw32(s, lm)] = (_Float16)(xr[t][r][0] * inv * nw0a);
          hb[sw32(s, 16 + lm)] = (_Float16)(xr[t][r][1] * inv * nw0b);
        }
      }
    }
  }
  __syncthreads();

  // ---- phase 2: q/k/v = MFMA(h, W) + head rmsnorm + RoPE; v -> vT ----
  // nt = u&1 is wave-constant (u steps by 4) -> hoist + pin the weights
  {
    const int ntw = wv & 1;
    const int d = ntw * 16 + lm;
    h8 bq = pin8(*(const h8*)(W16 + (ntw * 16 + lm) * 32 + lq * 8));
    h8 bk = pin8(*(const h8*)(W16 + 1024 + (ntw * 16 + lm) * 32 + lq * 8));
    h8 bv = pin8(*(const h8*)(W16 + 2048 + (ntw * 16 + lm) * 32 + lq * 8));
    for (int u = wv; u < MT * 2; u += 4) {
      const int mt = u >> 1;
      h8 aH = *(const h8*)(hb + sw32(mt * 16 + lm, lq * 8));
      float rc[4], rs[4];
      if (TEMPORAL) {
#pragma unroll
        for (int r = 0; r < 4; r++) {
          float2 cs = rope[(mt * 16 + lq * 4 + r) * 4 + (hd & 3)];
          rc[r] = cs.x; rs[r] = cs.y;
        }
      }
      fx4 aq = mfma16(aH, bq, fz);
      fx4 ak = mfma16(aH, bk, fz);
      fx4 av = mfma16(aH, bv, fz);
#pragma unroll
      for (int r = 0; r < 4; r++) {
        int s = mt * 16 + lq * 4 + r;
        float q1 = aq[r], k1 = ak[r];
        float qv = q1 * rsq_(red8(q1 * q1) * 0.125f + 1e-6f) * qw;
        float kv = k1 * rsq_(red8(k1 * k1) * 0.125f + 1e-6f) * kw;
        if (TEMPORAL) {
          float qp = __shfl_xor(qv, 4);
          float kp = __shfl_xor(kv, 4);
          qv = (hd < 4) ? (qv * rc[r] - qp * rs[r]) : (qv * rc[r] + qp * rs[r]);
          kv = (hd < 4) ? (kv * rc[r] - kp * rs[r]) : (kv * rc[r] + kp * rs[r]);
        }
        if (SV == SP || s < SV) {
          qb[sw32(s, d)] = (_Float16)(qv * qscale);  // exp2-ready
          kb[sw32(s, d)] = (_Float16)kv;
        }
      }
      // v -> vT[d][s], packed pairs (cols s0..s0+3, same 16-block)
      const int s0 = mt * 16 + lq * 4;
      const int va = vt_idx(d, s0);
      if (SV == SP || s0 + 1 < SV) *(h2*)(vT + va) = pkrtz(av[0], av[1]);
      if (SV == SP || s0 + 3 < SV) *(h2*)(vT + va + 2) = pkrtz(av[2], av[3]);
    }
  }
  if (!TEMPORAL) {
    // zero vT cols [134,160) so padded-K PV chunks multiply P*0 (finite)
    for (int idx = tid; idx < 32 * 13; idx += 256) {
      int d = idx / 13, c = 2 * SLOTS_ + 2 * (idx % 13);
      *(h2*)(vT + d * VSTRIDE + c) = pkrtz(0.f, 0.f);
    }
    // ones row 32: PV A-rows 8..15 read it -> C rows 8..15 = softmax denom
    for (int idx = tid; idx < VSTRIDE / 2; idx += 256) {
      *(h2*)(vT + 32 * VSTRIDE + 2 * idx) = pkrtz(1.f, 1.f);
    }
  }
  __syncthreads();

  // ---- phase 3: MFMA attention, PINNED hoist, pair-interleaved ----
  {
    const int h = wv;
    const h8 z8 = {};
    const h4 ones4 = {(_Float16)1.f, (_Float16)1.f, (_Float16)1.f, (_Float16)1.f};
    const bool vlane = (lm < 8);
    const int dv = h * 8 + (lm & 7);
    const int vrow = (!TEMPORAL && !vlane) ? 32 : dv;

    auto loadK = [&](int kt) {
      return pin8(*(const h8*)(kb + sw32(kt * 16 + lm, lq * 8)));
    };
    auto loadV = [&](int kt) {
      h4 v = *(const h4*)(vT + vt_idx(vrow, kt * 16 + lq * 4));
      v = pin4(v);
      return (TEMPORAL && !vlane) ? ones4 : v;
    };
    auto loadQ = [&](int mt) {
      h8 b = pin8(*(const h8*)(qb + sw32(mt * 16 + lm, lq * 8)));
      return (lq == h) ? b : z8;  // keep head-h dims only
    };
    auto maskx = [&](float x, int kidx, int mode, int q) {
      // mode 0: none; 1: keep kidx<67; 2: keep kidx>=67; 3: keep kidx<134;
      // 4: keep same-sequence & kidx<134
      if (mode == 1) return (kidx < SLOTS_) ? x : 0.f;
      if (mode == 2) return (kidx >= SLOTS_) ? x : 0.f;
      if (mode == 3) return (kidx < 2 * SLOTS_) ? x : 0.f;
      if (mode == 4) {
        bool ok = (kidx < 2 * SLOTS_) && ((kidx < SLOTS_) == (q < SLOTS_));
        return ok ? x : 0.f;
      }
      return x;
    };
    auto pvstep = [&](const h4& av, int kt, int mode, int q, const fx4& sc,
                      fx4& oacc) {
      float ev[4];
#pragma unroll
      for (int r = 0; r < 4; r++) {
        int kidx = kt * 16 + lq * 4 + r;
        ev[r] = maskx(__builtin_amdgcn_exp2f(sc[r]), kidx, mode, q);
      }
      H4u pT;
      pT.h[0] = pkrtz(ev[0], ev[1]); pT.h[1] = pkrtz(ev[2], ev[3]);
      oacc = mfma16k16(av, pT.v, oacc);
    };
    auto finish = [&](int mt, fx4& oa) {
      int q = mt * 16 + lm;
      // C rows 8..15 (lanes lq>=2) hold lsum; swap over to lanes lq<2
      float lsum = __shfl_xor(oa[0], 32);
      float inv = rcp_(lsum);
      if (lq < 2 && (SV == SP || q < SV)) {
        H4u ov;
        ov.h[0] = pkrtz(oa[0] * inv, oa[1] * inv);
        ov.h[1] = pkrtz(oa[2] * inv, oa[3] * inv);
        *(h4*)(hb + sw32(q, h * 8 + lq * 4)) = ov.v;  // h dead -> o
      }
    };

    if (TEMPORAL) {
      // pinned hoist aK/aV once; bQ per pair; 2 chains per pair (r14: 4 hurt)
      h8 aK[MT]; h4 aV[MT];
#pragma unroll
      for (int kt = 0; kt < MT; kt++) { aK[kt] = loadK(kt); aV[kt] = loadV(kt); }
#pragma unroll
      for (int mtp = 0; mtp < MT / 2; mtp++) {
        h8 bQ0 = loadQ(2 * mtp), bQ1 = loadQ(2 * mtp + 1);
        fx4 o0 = fz, o1 = fz;
#pragma unroll
        for (int kt = 0; kt < MT; kt++) {
          fx4 s0 = mfma16(aK[kt], bQ0, fz);
          fx4 s1 = mfma16(aK[kt], bQ1, fz);
          pvstep(aV[kt], kt, 0, 0, s0, o0);
          pvstep(aV[kt], kt, 0, 0, s1, o1);
        }
        finish(2 * mtp, o0);
        finish(2 * mtp + 1, o1);
      }
    } else {
      // section A: kt window 0..4, pairs (0,1),(2,3) — seq0 queries
      {
        h8 aKw[5]; h4 aVw[5];
#pragma unroll
        for (int kt = 0; kt < 5; kt++) { aKw[kt] = loadK(kt); aVw[kt] = loadV(kt); }
#pragma unroll
        for (int mtp = 0; mtp < 2; mtp++) {
          h8 bQ0 = loadQ(2 * mtp), bQ1 = loadQ(2 * mtp + 1);
          fx4 o0 = fz, o1 = fz;
#pragma unroll
          for (int kt = 0; kt < 5; kt++) {
            int mode = (kt == 4) ? 1 : 0;
            fx4 s0 = mfma16(aKw[kt], bQ0, fz);
            fx4 s1 = mfma16(aKw[kt], bQ1, fz);
            pvstep(aVw[kt], kt, mode, 0, s0, o0);
            pvstep(aVw[kt], kt, mode, 0, s1, o1);
          }
          finish(2 * mtp, o0);
          finish(2 * mtp + 1, o1);
        }
      }
      // section B: boundary tile mt=4, full kt sweep, per-q mask
      {
        h8 aKw[9]; h4 aVw[9];
#pragma unroll
        for (int kt = 0; kt < 9; kt++) { aKw[kt] = loadK(kt); aVw[kt] = loadV(kt); }
        h8 bQ = loadQ(4);
        fx4 oa = fz;
        const int q = 4 * 16 + lm;
#pragma unroll
        for (int kt = 0; kt < 9; kt++) {
          fx4 sc = mfma16(aKw[kt], bQ, fz);
          pvstep(aVw[kt], kt, 4, q, sc, oa);
        }
        finish(4, oa);
      }
      // section C: kt window 4..8, pairs (5,6),(7,8) — seq1 queries
      {
        h8 aKw[5]; h4 aVw[5];
#pragma unroll
        for (int kt = 0; kt < 5; kt++) {
          aKw[kt] = loadK(kt + 4); aVw[kt] = loadV(kt + 4);
        }
#pragma unroll
        for (int mtp = 0; mtp < 2; mtp++) {
          int m0 = 5 + 2 * mtp;
          h8 bQ0 = loadQ(m0), bQ1 = loadQ(m0 + 1);
          fx4 o0 = fz, o1 = fz;
#pragma unroll
          for (int kt = 0; kt < 5; kt++) {
            int mode = (kt == 0) ? 2 : (kt == 4 ? 3 : 0);
            fx4 s0 = mfma16(aKw[kt], bQ0, fz);
            fx4 s1 = mfma16(aKw[kt], bQ1, fz);
            pvstep(aVw[kt], kt + 4, mode, 0, s0, o0);
            pvstep(aVw[kt], kt + 4, mode, 0, s1, o1);
          }
          finish(m0, o0);
          finish(m0 + 1, o1);
        }
      }
    }
  }
  __syncthreads();

  // ---- phase 4 (fused): ao = MFMA(o, Wo); x += rms(ao); h2 = rms(x) -> hb.
  {
    // mt-invariant weights: hoist + pin once
    h8 b0 = pin8(*(const h8*)(W16 + 3072 + lm * 32 + lq * 8));
    h8 b1 = pin8(*(const h8*)(W16 + 3072 + (16 + lm) * 32 + lq * 8));
#pragma unroll
    for (int t = 0; t < MTW; t++) {
      int mt = wv + 4 * t;
      if (mt < MT) {
        h8 aO = *(const h8*)(hb + sw32(mt * 16 + lm, lq * 8));
        fx4 a0 = mfma16(aO, b0, fz);
        fx4 a1 = mfma16(aO, b1, fz);
#pragma unroll
        for (int r = 0; r < 4; r++) {
          int s = mt * 16 + lq * 4 + r;
          float p = bfly16(a0[r] * a0[r] + a1[r] * a1[r]);
          float inv = rsq_(p * (1.0f / E_) + 1e-6f);
          xr[t][r][0] += a0[r] * inv * nw1a;
          xr[t][r][1] += a1[r] * inv * nw1b;
          float q2 = bfly16(xr[t][r][0] * xr[t][r][0] + xr[t][r][1] * xr[t][r][1]);
          float inv2 = rsq_(q2 * (1.0f / E_) + 1e-6f);
          if (SV == SP || s < SV) {
            hb[sw32(s, lm)] = (_Float16)(xr[t][r][0] * inv2 * nw2a);
            hb[sw32(s, 16 + lm)] = (_Float16)(xr[t][r][1] * inv2 * nw2b);
          }
        }
      }
    }
  }
  __syncthreads();

  // ---- phase 5: ffn = silu(MFMA(h2,Wg)) * MFMA(h2,Wvl) -> ffnb ----
  // nt = u&3 is wave-constant (u steps by 4) -> hoist + pin the weights
  {
    const int ntw = wv & 3;
    h8 bg = pin8(*(const h8*)(W16 + 4096 + (ntw * 16 + lm) * 32 + lq * 8));
    h8 bl = pin8(*(const h8*)(W16 + 6144 + (ntw * 16 + lm) * 32 + lq * 8));
    for (int u = wv; u < MT * 4; u += 4) {
      const int mt = u >> 2;
      h8 aH2 = *(const h8*)(hb + sw32(mt * 16 + lm, lq * 8));
      fx4 g = mfma16(aH2, bg, fz);
      fx4 vvv = mfma16(aH2, bl, fz);
#pragma unroll
      for (int r = 0; r < 4; r++) {
        int s = mt * 16 + lq * 4 + r;
        if (SV == SP || s < SV) {
          float gg = g[r];
          float sg = gg * rcp_(1.0f + __builtin_amdgcn_exp2f(gg * -1.4426950408889634f));
          ffnb[sw64(s, ntw * 16 + lm)] = (_Float16)(sg * vvv[r]);
        }
      }
    }
  }
  __syncthreads();

  // ---- phase 6 (fused): out = MFMA(ffn, Wout^T); x += rms(out); store X ----
  {
    // mt-invariant weights: hoist + pin once
    h8 b00 = pin8(*(const h8*)(W16 + 8192 + lm * 64 + lq * 8));
    h8 b01 = pin8(*(const h8*)(W16 + 8192 + lm * 64 + 32 + lq * 8));
    h8 b10 = pin8(*(const h8*)(W16 + 8192 + (16 + lm) * 64 + lq * 8));
    h8 b11 = pin8(*(const h8*)(W16 + 8192 + (16 + lm) * 64 + 32 + lq * 8));
#pragma unroll
    for (int t = 0; t < MTW; t++) {
      int mt = wv + 4 * t;
      if (mt < MT) {
        const int row = mt * 16 + lm;
        h8 a0 = *(const h8*)(ffnb + sw64(row, lq * 8));
        h8 a1 = *(const h8*)(ffnb + sw64(row, 32 + lq * 8));
        fx4 o0 = mfma16(a1, b01, mfma16(a0, b00, fz));
        fx4 o1 = mfma16(a1, b11, mfma16(a0, b10, fz));
#pragma unroll
        for (int r = 0; r < 4; r++) {
          int s = mt * 16 + lq * 4 + r;
          float p = bfly16(o0[r] * o0[r] + o1[r] * o1[r]);
          float inv = rsq_(p * (1.0f / E_) + 1e-6f);
          xr[t][r][0] += o0[r] * inv * nw3a;
          xr[t][r][1] += o1[r] * inv * nw3b;
          if (SV == SP || s < SV) {
            int off = base + s * stride;
            X[off + lm] = (_Float16)xr[t][r][0];
            X[off + 16 + lm] = (_Float16)xr[t][r][1];
          }
        }
        // fold final rmsnorm + output extract into last spatial layer: the
        // 48 output tokens are rows 131..133 of blocks with bid%64 == 63
        if (LAST && mt == MT - 1 && (bid & (T_ / 2 - 1)) == (T_ / 2 - 1)) {
          const int b = bid / (T_ / 2);
#pragma unroll
          for (int r = 0; r < 4; r++) {
            int s = mt * 16 + lq * 4 + r;
            int j = s - (SLOTS_ + OBS_);
            float p2 = bfly16(xr[t][r][0] * xr[t][r][0] + xr[t][r][1] * xr[t][r][1]);
            if (j >= 0 && j < 3) {
              float inv2 = rsq_(p2 * (1.0f / E_) + 1e-6f);
              out[j * (B_ * E_) + b * E_ + lm] = xr[t][r][0] * inv2 * fnw[lm];
              out[j * (B_ * E_) + b * E_ + 16 + lm] = xr[t][r][1] * inv2 * fnw[16 + lm];
            }
          }
        }
      }
    }
  }
}

__global__ __launch_bounds__(256, 4) void attn_spatial_embed_kernel(
    _Float16* __restrict__ X, const _Float16* __restrict__ W16,
    const float* __restrict__ norm4, const float* __restrict__ qkn,
    EPtrs ep) {
  block_body<2 * SLOTS_, 144, false, false, true>(
      X, W16, norm4, qkn, nullptr, nullptr, nullptr, ep, blockIdx.x);
}

__global__ __launch_bounds__(256, 4) void attn_spatial_kernel(
    _Float16* __restrict__ X, const _Float16* __restrict__ W16,
    const float* __restrict__ norm4, const float* __restrict__ qkn) {
  EPtrs ep{};
  block_body<2 * SLOTS_, 144, false, false, false>(
      X, W16, norm4, qkn, nullptr, nullptr, nullptr, ep, blockIdx.x);
}

__global__ __launch_bounds__(256, 4) void attn_spatial_last_kernel(
    _Float16* __restrict__ X, const _Float16* __restrict__ W16,
    const float* __restrict__ norm4, const float* __restrict__ qkn,
    const float* __restrict__ fnw, float* __restrict__ out) {
  EPtrs ep{};
  block_body<2 * SLOTS_, 144, false, true, false>(
      X, W16, norm4, qkn, nullptr, fnw, out, ep, blockIdx.x);
}

__global__ __launch_bounds__(256, 4) void attn_temporal_kernel(
    _Float16* __restrict__ X, const _Float16* __restrict__ W16,
    const float* __restrict__ norm4, const float* __restrict__ qkn,
    const float2* __restrict__ rope) {
  EPtrs ep{};
  block_body<T_, 128, true, false, false>(
      X, W16, norm4, qkn, rope, nullptr, nullptr, ep, blockIdx.x);
}

extern "C" void kernel_launch(void* const* d_in, const int* in_sizes, int n_in,
                              void* d_out, int out_size, void* d_ws, size_t ws_size,
                              hipStream_t stream) {
  (void)in_sizes; (void)n_in; (void)out_size; (void)ws_size;
  const float* obs          = (const float*)d_in[0];
  const float* W_val        = (const float*)d_in[1];
  const float* b_val        = (const float*)d_in[2];
  const float* input_norm_w = (const float*)d_in[3];
  const float* dim_embed    = (const float*)d_in[4];
  const float* cls_tokens   = (const float*)d_in[5];
  const float* final_norm_w = (const float*)d_in[6];
  const float* s_n4   = (const float*)d_in[14];
  const float* s_qkn  = (const float*)d_in[15];
  const float* t_n4   = (const float*)d_in[23];
  const float* t_qkn  = (const float*)d_in[24];

  _Float16* X = (_Float16*)d_ws;  // fp16 residual stream, 8.78 MB
  _Float16* W16 = (_Float16*)((char*)d_ws + X16_BYTES);  // 5*10240 halves
  float2* rope = (float2*)((char*)d_ws + ROPE_OFF);      // 4 KB cos/sin
  float* out = (float*)d_out;

  WPtrs wp;
  wp.sWq   = (const float*)d_in[7];
  wp.sWk   = (const float*)d_in[8];
  wp.sWv   = (const float*)d_in[9];
  wp.sWo   = (const float*)d_in[10];
  wp.sWg   = (const float*)d_in[11];
  wp.sWvl  = (const float*)d_in[12];
  wp.sWout = (const float*)d_in[13];
  wp.tWq   = (const float*)d_in[16];
  wp.tWk   = (const float*)d_in[17];
  wp.tWv   = (const float*)d_in[18];
  wp.tWo   = (const float*)d_in[19];
  wp.tWg   = (const float*)d_in[20];
  wp.tWvl  = (const float*)d_in[21];
  wp.tWout = (const float*)d_in[22];

  EPtrs ep;
  ep.obs = obs; ep.Wval = W_val; ep.bval = b_val;
  ep.innw = input_norm_w; ep.dimemb = dim_embed; ep.cls = cls_tokens;

  setup_kernel<<<CVT_BLOCKS + 1, 256, 0, stream>>>(wp, W16, rope);

  const int N4 = 4 * E_;   // 128
  const int QN = 2 * HD_;  // 16

  // layer 0 spatial computes the embed in phase 1 (no separate embed pass)
  attn_spatial_embed_kernel<<<B_ * T_ / 2, 256, 0, stream>>>(
      X, W16, s_n4, s_qkn, ep);
  attn_temporal_kernel<<<B_ * SLOTS_, 256, 0, stream>>>(
      X, W16 + 3 * WBLK, t_n4, t_qkn, rope);
  attn_spatial_kernel<<<B_ * T_ / 2, 256, 0, stream>>>(
      X, W16 + 1 * WBLK, s_n4 + N4, s_qkn + QN);
  attn_temporal_kernel<<<B_ * SLOTS_, 256, 0, stream>>>(
      X, W16 + 4 * WBLK, t_n4 + N4, t_qkn + QN, rope);
  attn_spatial_last_kernel<<<B_ * T_ / 2, 256, 0, stream>>>(
      X, W16 + 2 * WBLK, s_n4 + 2 * N4, s_qkn + 2 * QN, final_norm_w, out);
}